// Round 2
// baseline (5544.766 us; speedup 1.0000x reference)
//
#include <hip/hip_runtime.h>
#include <cmath>
#include <cfloat>

#define B_   256
#define N_   100
#define D_   100
#define BN_  25600

// node -> subnet id (partition), from _SUBNET_MAP (1-indexed in python)
__device__ const int d_node2k[100] = {
 0,0,0,0,0,0,0,0,0,
 1,1,1,1,1,1,
 2,2,2,2,2,2,2,2,
 3,3,3,3,3,3,3,
 4,4,4,
 5,5,5,5,
 6,6,6,6,6,6,6,6,6,6,6,6,6,
 0,0,0,0,0,0,0,0,
 1,1,1,1,1,1,1,1,
 2,2,2,2,2,2,2,
 3,3,3,3,3,
 4,4,
 5,5,5,5,5,5,5,5,5,
 6,6,6,6,6,6,6,6,6,6,6};

__device__ __forceinline__ double get_rho(int epoch){
    double t = 1.0 - (double)epoch / 600.0;
    return 0.8 + (1.0 - 0.8) * exp(-5.0 * t * t);
}

// ------------------------- misc small kernels -------------------------
__global__ void k_zero(double* acc){
    if (threadIdx.x == 0){ acc[0] = 0.0; acc[1] = 0.0; }
}

__global__ void k_pos_embed(float* pose){
    int idx = blockIdx.x * blockDim.x + threadIdx.x;
    if (idx >= N_ * D_) return;
    int n = idx / D_;
    int i = idx - n * D_;
    double expo = (double)(2 * (i / 2)) / (double)D_;
    double ang  = (double)n / pow(10000.0, expo);
    pose[idx] = (float)((i & 1) ? cos(ang) : sin(ang));
}

// ------------------------- generic GEMM: C = A@W + bias -------------------------
// A: (25600, K), W: (K, Cd), C: (25600, Cd). 32x64 tile, 256 thr, 8 out/thr.
__global__ __launch_bounds__(256) void k_gemm_bias(
        const float* __restrict__ A, const float* __restrict__ W,
        const float* __restrict__ bias, float* __restrict__ C,
        int K, int Cd){
    __shared__ float As[32][33];
    int row0 = blockIdx.x * 32;
    int cl   = threadIdx.x & 63;
    int rg   = threadIdx.x >> 6;
    int c    = blockIdx.y * 64 + cl;
    bool cok = c < Cd;
    float acc[8];
    #pragma unroll
    for (int i = 0; i < 8; ++i) acc[i] = 0.f;
    for (int k0 = 0; k0 < K; k0 += 32){
        int kt = K - k0; if (kt > 32) kt = 32;
        for (int idx = threadIdx.x; idx < 1024; idx += 256){
            int r = idx >> 5, kk = idx & 31;
            As[r][kk] = (kk < kt) ? A[(size_t)(row0 + r) * K + k0 + kk] : 0.f;
        }
        __syncthreads();
        if (cok){
            for (int kk = 0; kk < kt; ++kk){
                float wv = W[(size_t)(k0 + kk) * Cd + c];
                #pragma unroll
                for (int i = 0; i < 8; ++i) acc[i] += As[rg * 8 + i][kk] * wv;
            }
        }
        __syncthreads();
    }
    if (cok){
        float bv = bias[c];
        #pragma unroll
        for (int i = 0; i < 8; ++i)
            C[(size_t)(row0 + rg * 8 + i) * Cd + c] = acc[i] + bv;
    }
}

// ------------------------- attention (per b,head) -------------------------
// qkv rows of 300: [q(100)|k(100)|v(100)]; head h slice [h*25, h*25+25)
__global__ __launch_bounds__(128) void k_attn(const float* __restrict__ qkv,
                                              float* __restrict__ o){
    int b = blockIdx.x >> 2;
    int h = blockIdx.x & 3;
    __shared__ float ks[100][26];
    __shared__ float vs[100][26];
    for (int i = threadIdx.x; i < 2500; i += 128){
        int n = i / 25, d = i - n * 25;
        const float* base = qkv + (size_t)(b * 100 + n) * 300 + h * 25 + d;
        ks[n][d] = base[100];
        vs[n][d] = base[200];
    }
    __syncthreads();
    int n = threadIdx.x;
    if (n < 100){
        float q[25];
        const float* qb = qkv + (size_t)(b * 100 + n) * 300 + h * 25;
        #pragma unroll
        for (int d = 0; d < 25; ++d) q[d] = qb[d];
        float m = -FLT_MAX, l = 0.f, acc[25];
        #pragma unroll
        for (int d = 0; d < 25; ++d) acc[d] = 0.f;
        for (int c = 0; c < 100; ++c){
            float s = 0.f;
            #pragma unroll
            for (int d = 0; d < 25; ++d) s += q[d] * ks[c][d];
            s *= 0.2f;   // 1/sqrt(25)
            if (s <= m){
                float p = expf(s - m);
                l += p;
                #pragma unroll
                for (int d = 0; d < 25; ++d) acc[d] += p * vs[c][d];
            } else {
                float sc = expf(m - s);
                l = l * sc + 1.f;
                #pragma unroll
                for (int d = 0; d < 25; ++d) acc[d] = acc[d] * sc + vs[c][d];
                m = s;
            }
        }
        float inv = 1.f / l;
        float* ob = o + (size_t)(b * 100 + n) * 100 + h * 25;
        #pragma unroll
        for (int d = 0; d < 25; ++d) ob[d] = acc[d] * inv;
    }
}

// ------------------------- fused add + LayerNorm -------------------------
// out = LN(xa + xb + (bias?)) * g + bt ; one wave per row of 100
__global__ __launch_bounds__(256) void k_add_ln(
        const float* __restrict__ xa, const float* __restrict__ xb,
        const float* __restrict__ bias, const float* __restrict__ g,
        const float* __restrict__ bt, float* __restrict__ out){
    int row  = blockIdx.x * 4 + (threadIdx.x >> 6);
    int lane = threadIdx.x & 63;
    const float* pa = xa + (size_t)row * 100;
    const float* pb = xb + (size_t)row * 100;
    int e1 = lane + 64;
    float v0 = pa[lane] + pb[lane] + (bias ? bias[lane] : 0.f);
    float v1 = 0.f;
    if (e1 < 100) v1 = pa[e1] + pb[e1] + (bias ? bias[e1] : 0.f);
    float s = v0 + v1;
    #pragma unroll
    for (int m = 32; m >= 1; m >>= 1) s += __shfl_xor(s, m, 64);
    float mean = s / 100.f;
    float d0 = v0 - mean;
    float d1 = (e1 < 100) ? (v1 - mean) : 0.f;
    float s2 = d0 * d0 + d1 * d1;
    #pragma unroll
    for (int m = 32; m >= 1; m >>= 1) s2 += __shfl_xor(s2, m, 64);
    float rstd = 1.f / sqrtf(s2 / 100.f + 1e-5f);
    float* po = out + (size_t)row * 100;
    po[lane] = d0 * rstd * g[lane] + bt[lane];
    if (e1 < 100) po[e1] = d1 * rstd * g[e1] + bt[e1];
}

// ------------------------- fused FFN: out = act(x@Wa + ba) @ Wb -------------------------
// x: (25600,100), Wa: (100,F), Wb: (F,100). act 0=relu, 1=leaky(0.01). 16 rows/block.
__global__ __launch_bounds__(256) void k_ffn(
        const float* __restrict__ x, const float* __restrict__ Wa,
        const float* __restrict__ ba, const float* __restrict__ Wb,
        float* __restrict__ out, int F, int act){
    __shared__ float xs[16][104];
    __shared__ float hs[16][66];
    __shared__ float wbs[64][112];
    int row0 = blockIdx.x * 16;
    int tid  = threadIdx.x;
    for (int idx = tid; idx < 1600; idx += 256){
        int r = idx / 100, d = idx - r * 100;
        xs[r][d] = x[(size_t)(row0 + r) * 100 + d];
    }
    float acc[7];
    #pragma unroll
    for (int j = 0; j < 7; ++j) acc[j] = 0.f;
    int f  = tid & 63;
    int wv = tid >> 6;
    int r  = tid >> 4, c0 = tid & 15;
    __syncthreads();
    for (int f0 = 0; f0 < F; f0 += 64){
        float hv[4];
        #pragma unroll
        for (int ii = 0; ii < 4; ++ii) hv[ii] = ba[f0 + f];
        for (int k = 0; k < 100; ++k){
            float wa = Wa[(size_t)k * F + f0 + f];
            #pragma unroll
            for (int ii = 0; ii < 4; ++ii) hv[ii] += xs[wv + 4 * ii][k] * wa;
        }
        if (act == 0){
            #pragma unroll
            for (int ii = 0; ii < 4; ++ii) hv[ii] = hv[ii] > 0.f ? hv[ii] : 0.f;
        } else {
            #pragma unroll
            for (int ii = 0; ii < 4; ++ii) hv[ii] = hv[ii] > 0.f ? hv[ii] : 0.01f * hv[ii];
        }
        __syncthreads();   // prior chunk fully consumed
        #pragma unroll
        for (int ii = 0; ii < 4; ++ii) hs[wv + 4 * ii][f] = hv[ii];
        for (int idx = tid; idx < 6400; idx += 256){
            int fr = idx / 100, d = idx - fr * 100;
            wbs[fr][d] = Wb[(size_t)(f0 + fr) * 100 + d];
        }
        __syncthreads();
        for (int ff = 0; ff < 64; ++ff){
            float h = hs[r][ff];
            #pragma unroll
            for (int j = 0; j < 7; ++j) acc[j] += h * wbs[ff][c0 + 16 * j];
        }
    }
    #pragma unroll
    for (int j = 0; j < 7; ++j){
        int c = c0 + 16 * j;
        if (c < 100) out[(size_t)(row0 + r) * 100 + c] = acc[j];
    }
}

// ------------------------- subnet means + cosine cost -------------------------
__global__ __launch_bounds__(256) void k_subnet_cost(const float* __restrict__ feat,
                                                     float* __restrict__ cost){
    int b = blockIdx.x;
    __shared__ float fs[100][101];
    __shared__ float sf[7][101];
    __shared__ float nf[100];
    __shared__ float ns[7];
    int tid = threadIdx.x;
    for (int idx = tid; idx < 10000; idx += 256){
        int n = idx / 100, d = idx - n * 100;
        fs[n][d] = feat[(size_t)(b * 100 + n) * 100 + d];
    }
    __syncthreads();
    const float cnt[7] = {17.f, 14.f, 15.f, 12.f, 5.f, 13.f, 24.f};
    for (int idx = tid; idx < 700; idx += 256){
        int k = idx / 100, d = idx - k * 100;
        float s = 0.f;
        for (int n = 0; n < 100; ++n) if (d_node2k[n] == k) s += fs[n][d];
        sf[k][d] = s / (cnt[k] + 1e-6f);
    }
    __syncthreads();
    if (tid < 100){
        float s = 0.f;
        for (int d = 0; d < 100; ++d) s += fs[tid][d] * fs[tid][d];
        float nv = sqrtf(s);
        nf[tid] = nv > 1e-12f ? nv : 1e-12f;
    }
    if (tid >= 128 && tid < 135){
        int k = tid - 128;
        float s = 0.f;
        for (int d = 0; d < 100; ++d) s += sf[k][d] * sf[k][d];
        float nv = sqrtf(s);
        ns[k] = nv > 1e-12f ? nv : 1e-12f;
    }
    __syncthreads();
    for (int idx = tid; idx < 700; idx += 256){
        int n = idx / 7, k = idx - n * 7;
        float s = 0.f;
        for (int d = 0; d < 100; ++d) s += fs[n][d] * sf[k][d];
        cost[(size_t)b * 700 + n * 7 + k] = s / (nf[n] * ns[k]);
    }
}

// ------------------------- sinkhorn (f64, per image, cold start) -------------------------
__global__ __launch_bounds__(128) void k_sinkhorn(const float* __restrict__ cost,
        float* __restrict__ qplan, float* __restrict__ qual,
        const int* __restrict__ ep){
    int b   = blockIdx.x;
    int tid = threadIdx.x;
    __shared__ double Qm[100][8];
    __shared__ double av[100];
    __shared__ double bv[8];
    __shared__ double b2v[8];
    __shared__ int s_stop;
    double rho = get_rho(ep[0]);
    const double prior[7] = {17.0/100.0, 14.0/100.0, 15.0/100.0, 12.0/100.0,
                             5.0/100.0, 13.0/100.0, 24.0/100.0};
    if (tid < 100){
        double c[7]; double mx = -1e300;
        for (int k = 0; k < 7; ++k){
            c[k] = (double)cost[(size_t)b * 700 + tid * 7 + k];
            if (c[k] > mx) mx = c[k];
        }
        double se = 0.0;
        for (int k = 0; k < 7; ++k) se += exp(c[k] - mx);
        double lse = mx + log(se);
        for (int k = 0; k < 7; ++k) Qm[tid][k] = exp(-((lse - c[k]) / 0.1));
        Qm[tid][7] = 1.0;   // exp(-0/eps)
    }
    if (tid < 8) bv[tid] = 1.0 / 8.0;
    if (tid == 0) s_stop = 0;
    __syncthreads();
    const double fi = 1.0 / 1.1;      // gamma/(gamma+eps)
    int j = tid >> 4, l16 = tid & 15;
    double Pbj = (j < 7) ? rho * prior[j] : (1.0 - rho);
    for (int it = 0; it < 50; ++it){
        if (tid < 100){
            double s = 0.0;
            #pragma unroll
            for (int k = 0; k < 8; ++k) s += Qm[tid][k] * bv[k];
            av[tid] = 0.01 / s;       // Pa = 1/100
        }
        __syncthreads();
        double p = 0.0;
        for (int n = l16; n < 100; n += 16) p += Qm[n][j] * av[n];
        p += __shfl_xor(p, 8, 16);
        p += __shfl_xor(p, 4, 16);
        p += __shfl_xor(p, 2, 16);
        p += __shfl_xor(p, 1, 16);
        if (l16 == 0){
            double nb = Pbj / p;
            if (j < 7) nb = pow(nb, fi);
            b2v[j] = nb;
        }
        __syncthreads();
        if (tid == 0){
            double e2 = 0.0;
            #pragma unroll
            for (int k = 0; k < 8; ++k){
                double d = b2v[k] - bv[k];
                e2 += d * d;
                bv[k] = b2v[k];
            }
            s_stop = (e2 <= 1e-12) ? 1 : 0;   // err = sqrt(e2) <= 1e-6
        }
        __syncthreads();
        if (s_stop) break;
    }
    if (tid < 100){
        float q = 0.f;
        for (int k = 0; k < 7; ++k){
            double pl = 100.0 * av[tid] * Qm[tid][k] * bv[k];
            float pf = (float)pl;
            qplan[(size_t)b * 700 + tid * 7 + k] = pf;
            q += pf;
        }
        qual[(size_t)b * 100 + tid] = q;
    }
}

// ------------------------- selection: quantile, noise, stable argsort rank, mask -------------------------
__global__ __launch_bounds__(128) void k_select(const float* __restrict__ qual,
        const float* __restrict__ qplan, const float* __restrict__ randK,
        const int* __restrict__ ep, float* __restrict__ maskb){
    int b   = blockIdx.x;
    int tid = threadIdx.x;
    __shared__ float qs[100];
    __shared__ float sorted_s[100];
    __shared__ float noise_s[100];
    __shared__ float thr_f;
    if (tid < 100) qs[tid] = qual[(size_t)b * 100 + tid];
    __syncthreads();
    if (tid < 100){
        float q = qs[tid];
        int cl = 0, ce = 0;
        for (int m = 0; m < 100; ++m){ cl += (qs[m] < q); ce += (qs[m] == q); }
        for (int r2 = cl; r2 < cl + ce; ++r2) sorted_s[r2] = q;
    }
    __syncthreads();
    if (tid == 0){
        double rho = get_rho(ep[0]);
        double pos = (1.0 - rho) * 99.0;
        int lo = (int)floor(pos);
        if (lo > 98) lo = 98; if (lo < 0) lo = 0;
        double fr = pos - (double)lo;
        double thr = (double)sorted_s[lo] + ((double)sorted_s[lo + 1] - (double)sorted_s[lo]) * fr;
        thr_f = (float)thr;
    }
    __syncthreads();
    if (tid < 100){
        float nz = 0.f;
        if (!(qs[tid] < thr_f)){
            for (int k = 0; k < 7; ++k)
                nz += qplan[(size_t)b * 700 + tid * 7 + k] * randK[b * 7 + k];
        }
        noise_s[tid] = nz;
    }
    __syncthreads();
    if (tid < 100){
        float nz = noise_s[tid];
        int rk = 0;
        for (int m = 0; m < 100; ++m){
            rk += (noise_s[m] < nz);
            rk += ((noise_s[m] == nz) && (m < tid));
        }
        // kept iff stable-argsort rank < LEN_KEEP(90) -> mask 0
        maskb[(size_t)b * 100 + tid] = (rk >= 90) ? 1.f : 0.f;
    }
}

// ------------------------- build decoder input -------------------------
__global__ void k_build_x(const float* __restrict__ imgs, const float* __restrict__ mtok,
        const float* __restrict__ maskb, const float* __restrict__ pose,
        float* __restrict__ x){
    int idx = blockIdx.x * 256 + threadIdx.x;
    if (idx >= B_ * N_ * D_) return;
    int d  = idx % 100;
    int bn = idx / 100;
    int n  = bn % 100;
    float v = (maskb[bn] == 0.f) ? imgs[idx] : mtok[d];
    x[idx] = v + pose[n * 100 + d];
}

// ------------------------- loss -------------------------
__global__ __launch_bounds__(256) void k_loss(const float* __restrict__ pred,
        const float* __restrict__ pb2, const float* __restrict__ imgs,
        const float* __restrict__ maskb, double* __restrict__ acc){
    int row  = blockIdx.x * 4 + (threadIdx.x >> 6);
    int lane = threadIdx.x & 63;
    const float* pp = pred + (size_t)row * 100;
    const float* pi = imgs + (size_t)row * 100;
    float d0 = pp[lane] + pb2[lane] - pi[lane];
    float s = d0 * d0;
    int e1 = lane + 64;
    if (e1 < 100){
        float d1 = pp[e1] + pb2[e1] - pi[e1];
        s += d1 * d1;
    }
    #pragma unroll
    for (int m = 32; m >= 1; m >>= 1) s += __shfl_xor(s, m, 64);
    if (lane == 0){
        float mk = maskb[row];
        atomicAdd(&acc[0], (double)((s / 100.f) * mk));
        atomicAdd(&acc[1], (double)mk);
    }
}

__global__ void k_final(const double* __restrict__ acc, float* __restrict__ out){
    if (threadIdx.x == 0) out[0] = (float)(acc[0] / acc[1]);
}

// ------------------------- host -------------------------
extern "C" void kernel_launch(void* const* d_in, const int* in_sizes, int n_in,
                              void* d_out, int out_size, void* d_ws, size_t ws_size,
                              hipStream_t stream){
    const float* imgs = (const float*)d_in[0];
    const float* Wqkv = (const float*)d_in[1];
    const float* bqkv = (const float*)d_in[2];
    const float* Wo   = (const float*)d_in[3];
    const float* bo   = (const float*)d_in[4];
    const float* ln1g = (const float*)d_in[5];
    const float* ln1b = (const float*)d_in[6];
    const float* W1   = (const float*)d_in[7];
    const float* b1   = (const float*)d_in[8];
    const float* W2   = (const float*)d_in[9];
    const float* b2   = (const float*)d_in[10];
    const float* ln2g = (const float*)d_in[11];
    const float* ln2b = (const float*)d_in[12];
    const float* mtok = (const float*)d_in[13];
    const float* pW1  = (const float*)d_in[14];
    const float* pb1  = (const float*)d_in[15];
    const float* pW2  = (const float*)d_in[16];
    const float* pb2  = (const float*)d_in[17];
    const float* rndK = (const float*)d_in[18];
    const int*   epoch = (const int*)d_in[19];

    float* ws     = (float*)d_ws;
    float* Xb     = ws;                       // 2,560,000
    float* Yb     = Xb + 2560000;             // 2,560,000
    float* Zb     = Yb + 2560000;             // 2,560,000
    float* QKVb   = Zb + 2560000;             // 7,680,000
    float* COSTb  = QKVb + 7680000;           // 179,200
    float* QPLANb = COSTb + 179200;           // 179,200
    float* QUALb  = QPLANb + 179200;          // 25,600
    float* MASKb  = QUALb + 25600;            // 25,600
    float* POSEb  = MASKb + 25600;            // 10,000
    double* ACCb  = (double*)(POSEb + 10000); // 2 doubles

    k_zero<<<1, 64, 0, stream>>>(ACCb);
    k_pos_embed<<<79, 128, 0, stream>>>(POSEb);

    auto layer = [&](const float* xi, float* xo, int l){
        k_gemm_bias<<<dim3(800, 5), 256, 0, stream>>>(xi, Wqkv + l * 30000, bqkv + l * 300, QKVb, 100, 300);
        k_attn<<<1024, 128, 0, stream>>>(QKVb, Yb);
        k_gemm_bias<<<dim3(800, 2), 256, 0, stream>>>(Yb, Wo + l * 10000, bo + l * 100, Zb, 100, 100);
        k_add_ln<<<6400, 256, 0, stream>>>(xi, Zb, (const float*)nullptr, ln1g + l * 100, ln1b + l * 100, xo);
        k_ffn<<<1600, 256, 0, stream>>>(xo, W1 + l * 204800, b1 + l * 2048, W2 + l * 204800, Yb, 2048, 0);
        k_add_ln<<<6400, 256, 0, stream>>>(xo, Yb, b2 + l * 100, ln2g + l * 100, ln2b + l * 100, xo);
    };

    // encoder on stop_gradient(imgs) -> feat in Xb
    layer(imgs, Xb, 0);
    layer(Xb, Xb, 1);

    k_subnet_cost<<<256, 256, 0, stream>>>(Xb, COSTb);
    k_sinkhorn<<<256, 128, 0, stream>>>(COSTb, QPLANb, QUALb, epoch);
    k_select<<<256, 128, 0, stream>>>(QUALb, QPLANb, rndK, epoch, MASKb);

    // decoder input overwrites Xb (feat no longer needed)
    k_build_x<<<10000, 256, 0, stream>>>(imgs, mtok, MASKb, POSEb, Xb);

    layer(Xb, Xb, 0);
    layer(Xb, Xb, 1);

    // predictor: leaky_relu(x@pW1+pb1)@pW2 (pb2 added in loss)
    k_ffn<<<1600, 256, 0, stream>>>(Xb, pW1, pb1, pW2, Yb, 1024, 1);

    k_loss<<<6400, 256, 0, stream>>>(Yb, pb2, imgs, MASKb, ACCb);
    k_final<<<1, 64, 0, stream>>>(ACCb, (float*)d_out);
}

// Round 3
// 1597.174 us; speedup vs baseline: 3.4716x; 3.4716x over previous
//
#include <hip/hip_runtime.h>
#include <cmath>
#include <cfloat>

#define B_   256
#define N_   100
#define D_   100
#define BN_  25600

typedef _Float16 f16;
typedef _Float16 f16x8 __attribute__((ext_vector_type(8)));
typedef float    f32x4 __attribute__((ext_vector_type(4)));

// node -> subnet id (partition), from _SUBNET_MAP (1-indexed in python)
__device__ const int d_node2k[100] = {
 0,0,0,0,0,0,0,0,0,
 1,1,1,1,1,1,
 2,2,2,2,2,2,2,2,
 3,3,3,3,3,3,3,
 4,4,4,
 5,5,5,5,
 6,6,6,6,6,6,6,6,6,6,6,6,6,
 0,0,0,0,0,0,0,0,
 1,1,1,1,1,1,1,1,
 2,2,2,2,2,2,2,
 3,3,3,3,3,
 4,4,
 5,5,5,5,5,5,5,5,5,
 6,6,6,6,6,6,6,6,6,6,6};

__device__ __forceinline__ double get_rho(int epoch){
    double t = 1.0 - (double)epoch / 600.0;
    return 0.8 + (1.0 - 0.8) * exp(-5.0 * t * t);
}

// ------------------------- misc small kernels -------------------------
__global__ void k_pos_embed(float* pose){
    int idx = blockIdx.x * blockDim.x + threadIdx.x;
    if (idx >= N_ * D_) return;
    int n = idx / D_;
    int i = idx - n * D_;
    double expo = (double)(2 * (i / 2)) / (double)D_;
    double ang  = (double)n / pow(10000.0, expo);
    pose[idx] = (float)((i & 1) ? cos(ang) : sin(ang));
}

// ------------------------- weight transposes (one-time, f32 -> f16) -------------------------
// WT[f][k] = W[k][f], k<100 else 0.  WT: (F,128) f16
__global__ __launch_bounds__(256) void k_transpose_a(const float* __restrict__ W,
        f16* __restrict__ WT, int F, int lg2F){
    int idx = blockIdx.x * 256 + threadIdx.x;
    if (idx >= (F << 7)) return;
    int f = idx & (F - 1);
    int k = idx >> lg2F;
    WT[(size_t)f * 128 + k] = (k < 100) ? (f16)W[(size_t)k * F + f] : (f16)0.f;
}

// WT[d][f] = W[f][d], d<100 else 0.  WT: (112,F) f16
__global__ __launch_bounds__(256) void k_transpose_b(const float* __restrict__ W,
        f16* __restrict__ WT, int F, int lg2F){
    int idx = blockIdx.x * 256 + threadIdx.x;
    if (idx >= 112 * F) return;
    int f = idx & (F - 1);
    int d = idx >> lg2F;
    WT[(size_t)d * F + f] = (d < 100) ? (f16)W[(size_t)f * 100 + d] : (f16)0.f;
}

// ------------------------- generic GEMM: C = A@W + bias -------------------------
__global__ __launch_bounds__(256) void k_gemm_bias(
        const float* __restrict__ A, const float* __restrict__ W,
        const float* __restrict__ bias, float* __restrict__ C,
        int K, int Cd){
    __shared__ float As[32][33];
    int row0 = blockIdx.x * 32;
    int cl   = threadIdx.x & 63;
    int rg   = threadIdx.x >> 6;
    int c    = blockIdx.y * 64 + cl;
    bool cok = c < Cd;
    float acc[8];
    #pragma unroll
    for (int i = 0; i < 8; ++i) acc[i] = 0.f;
    for (int k0 = 0; k0 < K; k0 += 32){
        int kt = K - k0; if (kt > 32) kt = 32;
        for (int idx = threadIdx.x; idx < 1024; idx += 256){
            int r = idx >> 5, kk = idx & 31;
            As[r][kk] = (kk < kt) ? A[(size_t)(row0 + r) * K + k0 + kk] : 0.f;
        }
        __syncthreads();
        if (cok){
            for (int kk = 0; kk < kt; ++kk){
                float wv = W[(size_t)(k0 + kk) * Cd + c];
                #pragma unroll
                for (int i = 0; i < 8; ++i) acc[i] += As[rg * 8 + i][kk] * wv;
            }
        }
        __syncthreads();
    }
    if (cok){
        float bv = bias[c];
        #pragma unroll
        for (int i = 0; i < 8; ++i)
            C[(size_t)(row0 + rg * 8 + i) * Cd + c] = acc[i] + bv;
    }
}

// ------------------------- attention (per b,head) -------------------------
__global__ __launch_bounds__(128) void k_attn(const float* __restrict__ qkv,
                                              float* __restrict__ o){
    int b = blockIdx.x >> 2;
    int h = blockIdx.x & 3;
    __shared__ float ks[100][26];
    __shared__ float vs[100][26];
    for (int i = threadIdx.x; i < 2500; i += 128){
        int n = i / 25, d = i - n * 25;
        const float* base = qkv + (size_t)(b * 100 + n) * 300 + h * 25 + d;
        ks[n][d] = base[100];
        vs[n][d] = base[200];
    }
    __syncthreads();
    int n = threadIdx.x;
    if (n < 100){
        float q[25];
        const float* qb = qkv + (size_t)(b * 100 + n) * 300 + h * 25;
        #pragma unroll
        for (int d = 0; d < 25; ++d) q[d] = qb[d];
        float m = -FLT_MAX, l = 0.f, acc[25];
        #pragma unroll
        for (int d = 0; d < 25; ++d) acc[d] = 0.f;
        for (int c = 0; c < 100; ++c){
            float s = 0.f;
            #pragma unroll
            for (int d = 0; d < 25; ++d) s += q[d] * ks[c][d];
            s *= 0.2f;
            if (s <= m){
                float p = expf(s - m);
                l += p;
                #pragma unroll
                for (int d = 0; d < 25; ++d) acc[d] += p * vs[c][d];
            } else {
                float sc = expf(m - s);
                l = l * sc + 1.f;
                #pragma unroll
                for (int d = 0; d < 25; ++d) acc[d] = acc[d] * sc + vs[c][d];
                m = s;
            }
        }
        float inv = 1.f / l;
        float* ob = o + (size_t)(b * 100 + n) * 100 + h * 25;
        #pragma unroll
        for (int d = 0; d < 25; ++d) ob[d] = acc[d] * inv;
    }
}

// ------------------------- fused add + LayerNorm -------------------------
__global__ __launch_bounds__(256) void k_add_ln(
        const float* __restrict__ xa, const float* __restrict__ xb,
        const float* __restrict__ bias, const float* __restrict__ g,
        const float* __restrict__ bt, float* __restrict__ out){
    int row  = blockIdx.x * 4 + (threadIdx.x >> 6);
    int lane = threadIdx.x & 63;
    const float* pa = xa + (size_t)row * 100;
    const float* pb = xb + (size_t)row * 100;
    int e1 = lane + 64;
    float v0 = pa[lane] + pb[lane] + (bias ? bias[lane] : 0.f);
    float v1 = 0.f;
    if (e1 < 100) v1 = pa[e1] + pb[e1] + (bias ? bias[e1] : 0.f);
    float s = v0 + v1;
    #pragma unroll
    for (int m = 32; m >= 1; m >>= 1) s += __shfl_xor(s, m, 64);
    float mean = s / 100.f;
    float d0 = v0 - mean;
    float d1 = (e1 < 100) ? (v1 - mean) : 0.f;
    float s2 = d0 * d0 + d1 * d1;
    #pragma unroll
    for (int m = 32; m >= 1; m >>= 1) s2 += __shfl_xor(s2, m, 64);
    float rstd = 1.f / sqrtf(s2 / 100.f + 1e-5f);
    float* po = out + (size_t)row * 100;
    po[lane] = d0 * rstd * g[lane] + bt[lane];
    if (e1 < 100) po[e1] = d1 * rstd * g[e1] + bt[e1];
}

// ------------------------- MFMA FFN: out = act(x@Wa + ba) @ Wb -------------------------
// x: (25600,100) f32.  WaT: (F,128) f16 (K padded).  WbT: (112,F) f16 (N padded).
// 128 rows/block, 4 waves x 32 rows. F-chunk = 64. act 0=relu, 1=leaky(0.01).
__global__ __launch_bounds__(256) void k_ffn_mfma(
        const float* __restrict__ x, const f16* __restrict__ WaT,
        const float* __restrict__ ba, const f16* __restrict__ WbT,
        float* __restrict__ out, int F, int act){
    __shared__ f16 xs [128 * 128];   // [row][k]  swizzled
    __shared__ f16 waT[ 64 * 128];   // [f_local][k]
    __shared__ f16 wbT[112 *  64];   // [d][f_local]
    __shared__ f16 hs [  4 * 32 * 64]; // per-wave [row][f_local]
    int tid  = threadIdx.x;
    int wv   = tid >> 6, lane = tid & 63;
    int l15  = lane & 15, lg = lane >> 4;
    int row0 = blockIdx.x * 128;

    // ---- stage x tile once: f32 -> f16, swizzled ----
    for (int c = tid; c < 2048; c += 256){
        int r = c >> 4, k8 = c & 15;
        const float* src = x + (size_t)(row0 + r) * 100 + k8 * 8;
        f16 tmp[8];
        if (k8 < 12){
            float4 v0 = *(const float4*)(src);
            float4 v1 = *(const float4*)(src + 4);
            tmp[0]=(f16)v0.x; tmp[1]=(f16)v0.y; tmp[2]=(f16)v0.z; tmp[3]=(f16)v0.w;
            tmp[4]=(f16)v1.x; tmp[5]=(f16)v1.y; tmp[6]=(f16)v1.z; tmp[7]=(f16)v1.w;
        } else if (k8 == 12){
            float4 v0 = *(const float4*)(src);
            tmp[0]=(f16)v0.x; tmp[1]=(f16)v0.y; tmp[2]=(f16)v0.z; tmp[3]=(f16)v0.w;
            tmp[4]=(f16)0.f; tmp[5]=(f16)0.f; tmp[6]=(f16)0.f; tmp[7]=(f16)0.f;
        } else {
            #pragma unroll
            for (int j = 0; j < 8; ++j) tmp[j] = (f16)0.f;
        }
        int addr = (r * 256 + k8 * 16) ^ ((r & 7) << 4);
        *(f16x8*)((char*)xs + addr) = *(const f16x8*)tmp;
    }

    f32x4 acc[2][7];
    #pragma unroll
    for (int rt = 0; rt < 2; ++rt)
        #pragma unroll
        for (int ct = 0; ct < 7; ++ct) acc[rt][ct] = (f32x4)0.f;

    int nch = F >> 6;
    for (int ch = 0; ch < nch; ++ch){
        int f0 = ch << 6;
        __syncthreads();   // previous chunk fully consumed
        // stage WaT chunk (64 x 128 f16)
        for (int c = tid; c < 1024; c += 256){
            int fl = c >> 4, k8 = c & 15;
            uint4 v = *(const uint4*)(WaT + (size_t)(f0 + fl) * 128 + k8 * 8);
            int addr = (fl * 256 + k8 * 16) ^ ((fl & 7) << 4);
            *(uint4*)((char*)waT + addr) = v;
        }
        // stage WbT chunk (112 x 64 f16)
        for (int c = tid; c < 896; c += 256){
            int d = c >> 3, f8 = c & 7;
            uint4 v = *(const uint4*)(WbT + (size_t)d * F + f0 + f8 * 8);
            int addr = (d * 128 + f8 * 16) ^ ((d & 7) << 4);
            *(uint4*)((char*)wbT + addr) = v;
        }
        __syncthreads();

        // ---- phase 1: H(32x64) = x_tile(32x128) @ WaT_chunk^T ----
        f32x4 h[2][4];
        #pragma unroll
        for (int rt = 0; rt < 2; ++rt)
            #pragma unroll
            for (int ct = 0; ct < 4; ++ct) h[rt][ct] = (f32x4)0.f;
        #pragma unroll
        for (int ks = 0; ks < 4; ++ks){
            int ko = ks * 64 + lg * 16;   // byte offset of 8 f16 along k
            int r0 = wv * 32 + l15;
            f16x8 a0 = *(const f16x8*)((char*)xs + ((r0 * 256 + ko) ^ ((r0 & 7) << 4)));
            int r1 = r0 + 16;
            f16x8 a1 = *(const f16x8*)((char*)xs + ((r1 * 256 + ko) ^ ((r1 & 7) << 4)));
            #pragma unroll
            for (int ct = 0; ct < 4; ++ct){
                int fr = ct * 16 + l15;
                f16x8 b = *(const f16x8*)((char*)waT + ((fr * 256 + ko) ^ ((fr & 7) << 4)));
                h[0][ct] = __builtin_amdgcn_mfma_f32_16x16x32_f16(a0, b, h[0][ct], 0, 0, 0);
                h[1][ct] = __builtin_amdgcn_mfma_f32_16x16x32_f16(a1, b, h[1][ct], 0, 0, 0);
            }
        }
        // bias + act + cvt -> hs (wave-private, no barrier needed)
        #pragma unroll
        for (int ct = 0; ct < 4; ++ct){
            float bav = ba[f0 + ct * 16 + l15];
            #pragma unroll
            for (int rt = 0; rt < 2; ++rt){
                #pragma unroll
                for (int reg = 0; reg < 4; ++reg){
                    float v = h[rt][ct][reg] + bav;
                    v = (v > 0.f) ? v : (act ? 0.01f * v : 0.f);
                    int row = rt * 16 + lg * 4 + reg;
                    int addr = wv * 4096 + ((row * 128 + (ct * 16 + l15) * 2) ^ ((row & 7) << 4));
                    *(f16*)((char*)hs + addr) = (f16)v;
                }
            }
        }
        // ---- phase 2: out += H(32x64) @ WbT_chunk^T(64x112) ----
        #pragma unroll
        for (int ks = 0; ks < 2; ++ks){
            int ko = ks * 64 + lg * 16;
            int r0 = l15;
            f16x8 a0 = *(const f16x8*)((char*)hs + (wv * 4096 + ((r0 * 128 + ko) ^ ((r0 & 7) << 4))));
            int r1 = l15 + 16;
            f16x8 a1 = *(const f16x8*)((char*)hs + (wv * 4096 + ((r1 * 128 + ko) ^ ((r1 & 7) << 4))));
            #pragma unroll
            for (int ct = 0; ct < 7; ++ct){
                int d = ct * 16 + l15;
                f16x8 b = *(const f16x8*)((char*)wbT + ((d * 128 + ko) ^ ((d & 7) << 4)));
                acc[0][ct] = __builtin_amdgcn_mfma_f32_16x16x32_f16(a0, b, acc[0][ct], 0, 0, 0);
                acc[1][ct] = __builtin_amdgcn_mfma_f32_16x16x32_f16(a1, b, acc[1][ct], 0, 0, 0);
            }
        }
    }

    // ---- epilogue: write out (cols < 100) ----
    #pragma unroll
    for (int rt = 0; rt < 2; ++rt){
        #pragma unroll
        for (int ct = 0; ct < 7; ++ct){
            int col = ct * 16 + l15;
            if (col < 100){
                #pragma unroll
                for (int reg = 0; reg < 4; ++reg){
                    int row = row0 + wv * 32 + rt * 16 + lg * 4 + reg;
                    out[(size_t)row * 100 + col] = acc[rt][ct][reg];
                }
            }
        }
    }
}

// ------------------------- subnet means + cosine cost -------------------------
__global__ __launch_bounds__(256) void k_subnet_cost(const float* __restrict__ feat,
                                                     float* __restrict__ cost){
    int b = blockIdx.x;
    __shared__ float fs[100][101];
    __shared__ float sf[7][101];
    __shared__ float nf[100];
    __shared__ float ns[7];
    int tid = threadIdx.x;
    for (int idx = tid; idx < 10000; idx += 256){
        int n = idx / 100, d = idx - n * 100;
        fs[n][d] = feat[(size_t)(b * 100 + n) * 100 + d];
    }
    __syncthreads();
    const float cnt[7] = {17.f, 14.f, 15.f, 12.f, 5.f, 13.f, 24.f};
    for (int idx = tid; idx < 700; idx += 256){
        int k = idx / 100, d = idx - k * 100;
        float s = 0.f;
        for (int n = 0; n < 100; ++n) if (d_node2k[n] == k) s += fs[n][d];
        sf[k][d] = s / (cnt[k] + 1e-6f);
    }
    __syncthreads();
    if (tid < 100){
        float s = 0.f;
        for (int d = 0; d < 100; ++d) s += fs[tid][d] * fs[tid][d];
        float nv = sqrtf(s);
        nf[tid] = nv > 1e-12f ? nv : 1e-12f;
    }
    if (tid >= 128 && tid < 135){
        int k = tid - 128;
        float s = 0.f;
        for (int d = 0; d < 100; ++d) s += sf[k][d] * sf[k][d];
        float nv = sqrtf(s);
        ns[k] = nv > 1e-12f ? nv : 1e-12f;
    }
    __syncthreads();
    for (int idx = tid; idx < 700; idx += 256){
        int n = idx / 7, k = idx - n * 7;
        float s = 0.f;
        for (int d = 0; d < 100; ++d) s += fs[n][d] * sf[k][d];
        cost[(size_t)b * 700 + n * 7 + k] = s / (nf[n] * ns[k]);
    }
}

// ------------------------- sinkhorn (f64, per image, cold start) -------------------------
__global__ __launch_bounds__(128) void k_sinkhorn(const float* __restrict__ cost,
        float* __restrict__ qplan, float* __restrict__ qual,
        const int* __restrict__ ep){
    int b   = blockIdx.x;
    int tid = threadIdx.x;
    __shared__ double Qm[100][8];
    __shared__ double av[100];
    __shared__ double bv[8];
    __shared__ double b2v[8];
    __shared__ int s_stop;
    double rho = get_rho(ep[0]);
    const double prior[7] = {17.0/100.0, 14.0/100.0, 15.0/100.0, 12.0/100.0,
                             5.0/100.0, 13.0/100.0, 24.0/100.0};
    if (tid < 100){
        double c[7]; double mx = -1e300;
        for (int k = 0; k < 7; ++k){
            c[k] = (double)cost[(size_t)b * 700 + tid * 7 + k];
            if (c[k] > mx) mx = c[k];
        }
        double se = 0.0;
        for (int k = 0; k < 7; ++k) se += exp(c[k] - mx);
        double lse = mx + log(se);
        for (int k = 0; k < 7; ++k) Qm[tid][k] = exp(-((lse - c[k]) / 0.1));
        Qm[tid][7] = 1.0;
    }
    if (tid < 8) bv[tid] = 1.0 / 8.0;
    if (tid == 0) s_stop = 0;
    __syncthreads();
    const double fi = 1.0 / 1.1;
    int j = tid >> 4, l16 = tid & 15;
    double Pbj = (j < 7) ? rho * prior[j] : (1.0 - rho);
    for (int it = 0; it < 50; ++it){
        if (tid < 100){
            double s = 0.0;
            #pragma unroll
            for (int k = 0; k < 8; ++k) s += Qm[tid][k] * bv[k];
            av[tid] = 0.01 / s;
        }
        __syncthreads();
        double p = 0.0;
        for (int n = l16; n < 100; n += 16) p += Qm[n][j] * av[n];
        p += __shfl_xor(p, 8, 16);
        p += __shfl_xor(p, 4, 16);
        p += __shfl_xor(p, 2, 16);
        p += __shfl_xor(p, 1, 16);
        if (l16 == 0){
            double nb = Pbj / p;
            if (j < 7) nb = pow(nb, fi);
            b2v[j] = nb;
        }
        __syncthreads();
        if (tid == 0){
            double e2 = 0.0;
            #pragma unroll
            for (int k = 0; k < 8; ++k){
                double d = b2v[k] - bv[k];
                e2 += d * d;
                bv[k] = b2v[k];
            }
            s_stop = (e2 <= 1e-12) ? 1 : 0;
        }
        __syncthreads();
        if (s_stop) break;
    }
    if (tid < 100){
        float q = 0.f;
        for (int k = 0; k < 7; ++k){
            double pl = 100.0 * av[tid] * Qm[tid][k] * bv[k];
            float pf = (float)pl;
            qplan[(size_t)b * 700 + tid * 7 + k] = pf;
            q += pf;
        }
        qual[(size_t)b * 100 + tid] = q;
    }
}

// ------------------------- selection -------------------------
__global__ __launch_bounds__(128) void k_select(const float* __restrict__ qual,
        const float* __restrict__ qplan, const float* __restrict__ randK,
        const int* __restrict__ ep, float* __restrict__ maskb){
    int b   = blockIdx.x;
    int tid = threadIdx.x;
    __shared__ float qs[100];
    __shared__ float sorted_s[100];
    __shared__ float noise_s[100];
    __shared__ float thr_f;
    if (tid < 100) qs[tid] = qual[(size_t)b * 100 + tid];
    __syncthreads();
    if (tid < 100){
        float q = qs[tid];
        int cl = 0, ce = 0;
        for (int m = 0; m < 100; ++m){ cl += (qs[m] < q); ce += (qs[m] == q); }
        for (int r2 = cl; r2 < cl + ce; ++r2) sorted_s[r2] = q;
    }
    __syncthreads();
    if (tid == 0){
        double rho = get_rho(ep[0]);
        double pos = (1.0 - rho) * 99.0;
        int lo = (int)floor(pos);
        if (lo > 98) lo = 98; if (lo < 0) lo = 0;
        double fr = pos - (double)lo;
        double thr = (double)sorted_s[lo] + ((double)sorted_s[lo + 1] - (double)sorted_s[lo]) * fr;
        thr_f = (float)thr;
    }
    __syncthreads();
    if (tid < 100){
        float nz = 0.f;
        if (!(qs[tid] < thr_f)){
            for (int k = 0; k < 7; ++k)
                nz += qplan[(size_t)b * 700 + tid * 7 + k] * randK[b * 7 + k];
        }
        noise_s[tid] = nz;
    }
    __syncthreads();
    if (tid < 100){
        float nz = noise_s[tid];
        int rk = 0;
        for (int m = 0; m < 100; ++m){
            rk += (noise_s[m] < nz);
            rk += ((noise_s[m] == nz) && (m < tid));
        }
        maskb[(size_t)b * 100 + tid] = (rk >= 90) ? 1.f : 0.f;
    }
}

// ------------------------- build decoder input -------------------------
__global__ void k_build_x(const float* __restrict__ imgs, const float* __restrict__ mtok,
        const float* __restrict__ maskb, const float* __restrict__ pose,
        float* __restrict__ x){
    int idx = blockIdx.x * 256 + threadIdx.x;
    if (idx >= B_ * N_ * D_) return;
    int d  = idx % 100;
    int bn = idx / 100;
    int n  = bn % 100;
    float v = (maskb[bn] == 0.f) ? imgs[idx] : mtok[d];
    x[idx] = v + pose[n * 100 + d];
}

// ------------------------- loss: two-stage reduction -------------------------
__global__ __launch_bounds__(256) void k_loss(const float* __restrict__ pred,
        const float* __restrict__ pb2, const float* __restrict__ imgs,
        const float* __restrict__ maskb, double* __restrict__ partial){
    int wv   = threadIdx.x >> 6;
    int row  = blockIdx.x * 4 + wv;
    int lane = threadIdx.x & 63;
    const float* pp = pred + (size_t)row * 100;
    const float* pi = imgs + (size_t)row * 100;
    float d0 = pp[lane] + pb2[lane] - pi[lane];
    float s = d0 * d0;
    int e1 = lane + 64;
    if (e1 < 100){
        float d1 = pp[e1] + pb2[e1] - pi[e1];
        s += d1 * d1;
    }
    #pragma unroll
    for (int m = 32; m >= 1; m >>= 1) s += __shfl_xor(s, m, 64);
    __shared__ float ls[4], lc[4];
    if (lane == 0){
        float mk = maskb[row];
        ls[wv] = (s / 100.f) * mk;
        lc[wv] = mk;
    }
    __syncthreads();
    if (threadIdx.x == 0){
        partial[2 * blockIdx.x]     = (double)(ls[0] + ls[1] + ls[2] + ls[3]);
        partial[2 * blockIdx.x + 1] = (double)(lc[0] + lc[1] + lc[2] + lc[3]);
    }
}

__global__ __launch_bounds__(256) void k_final(const double* __restrict__ partial,
                                               float* __restrict__ out){
    int tid = threadIdx.x;
    double s = 0.0, c = 0.0;
    for (int i = tid; i < 6400; i += 256){
        s += partial[2 * i];
        c += partial[2 * i + 1];
    }
    #pragma unroll
    for (int m = 32; m >= 1; m >>= 1){
        s += __shfl_xor(s, m, 64);
        c += __shfl_xor(c, m, 64);
    }
    __shared__ double ss[4], cs[4];
    if ((tid & 63) == 0){ ss[tid >> 6] = s; cs[tid >> 6] = c; }
    __syncthreads();
    if (tid == 0){
        double S = ss[0] + ss[1] + ss[2] + ss[3];
        double C = cs[0] + cs[1] + cs[2] + cs[3];
        out[0] = (float)(S / C);
    }
}

// ------------------------- host -------------------------
extern "C" void kernel_launch(void* const* d_in, const int* in_sizes, int n_in,
                              void* d_out, int out_size, void* d_ws, size_t ws_size,
                              hipStream_t stream){
    const float* imgs = (const float*)d_in[0];
    const float* Wqkv = (const float*)d_in[1];
    const float* bqkv = (const float*)d_in[2];
    const float* Wo   = (const float*)d_in[3];
    const float* bo   = (const float*)d_in[4];
    const float* ln1g = (const float*)d_in[5];
    const float* ln1b = (const float*)d_in[6];
    const float* W1   = (const float*)d_in[7];
    const float* b1   = (const float*)d_in[8];
    const float* W2   = (const float*)d_in[9];
    const float* b2   = (const float*)d_in[10];
    const float* ln2g = (const float*)d_in[11];
    const float* ln2b = (const float*)d_in[12];
    const float* mtok = (const float*)d_in[13];
    const float* pW1  = (const float*)d_in[14];
    const float* pb1  = (const float*)d_in[15];
    const float* pW2  = (const float*)d_in[16];
    const float* pb2  = (const float*)d_in[17];
    const float* rndK = (const float*)d_in[18];
    const int*   epoch = (const int*)d_in[19];

    float* ws     = (float*)d_ws;
    float* Xb     = ws;                       // 2,560,000 f
    float* Yb     = Xb + 2560000;             // 2,560,000 f
    float* AUX    = Yb + 2560000;             // 2,560,000 f (transposed weights + loss partials)
    float* QKVb   = AUX + 2560000;            // 7,680,000 f (also reused for attn-proj output)
    float* COSTb  = QKVb + 7680000;           // 179,200
    float* QPLANb = COSTb + 179200;           // 179,200
    float* QUALb  = QPLANb + 179200;          // 25,600
    float* MASKb  = QUALb + 25600;            // 25,600
    float* POSEb  = MASKb + 25600;            // 10,000

    f16* W1T0 = (f16*)(AUX);                  // 2048*128 f16
    f16* W1T1 = (f16*)(AUX + 131072);
    f16* W2T0 = (f16*)(AUX + 262144);         // 112*2048 f16
    f16* W2T1 = (f16*)(AUX + 319488);
    f16* PW1T = (f16*)(AUX + 376832);         // 1024*128 f16
    f16* PW2T = (f16*)(AUX + 442368);         // 112*1024 f16
    double* LOSSP = (double*)(AUX + 471040);  // 6400*2 f64

    // one-time weight transposes (f32 -> f16, padded)
    k_transpose_a<<<1024, 256, 0, stream>>>(W1,          W1T0, 2048, 11);
    k_transpose_a<<<1024, 256, 0, stream>>>(W1 + 204800, W1T1, 2048, 11);
    k_transpose_b<<< 896, 256, 0, stream>>>(W2,          W2T0, 2048, 11);
    k_transpose_b<<< 896, 256, 0, stream>>>(W2 + 204800, W2T1, 2048, 11);
    k_transpose_a<<< 512, 256, 0, stream>>>(pW1,         PW1T, 1024, 10);
    k_transpose_b<<< 448, 256, 0, stream>>>(pW2,         PW2T, 1024, 10);
    k_pos_embed<<<79, 128, 0, stream>>>(POSEb);

    auto layer = [&](const float* xi, float* xo, int l){
        k_gemm_bias<<<dim3(800, 5), 256, 0, stream>>>(xi, Wqkv + l * 30000, bqkv + l * 300, QKVb, 100, 300);
        k_attn<<<1024, 128, 0, stream>>>(QKVb, Yb);
        k_gemm_bias<<<dim3(800, 2), 256, 0, stream>>>(Yb, Wo + l * 10000, bo + l * 100, QKVb, 100, 100);
        k_add_ln<<<6400, 256, 0, stream>>>(xi, QKVb, (const float*)nullptr, ln1g + l * 100, ln1b + l * 100, xo);
        k_ffn_mfma<<<200, 256, 0, stream>>>(xo, (l ? W1T1 : W1T0), b1 + l * 2048,
                                            (l ? W2T1 : W2T0), Yb, 2048, 0);
        k_add_ln<<<6400, 256, 0, stream>>>(xo, Yb, b2 + l * 100, ln2g + l * 100, ln2b + l * 100, xo);
    };

    // encoder on stop_gradient(imgs) -> feat in Xb
    layer(imgs, Xb, 0);
    layer(Xb, Xb, 1);

    k_subnet_cost<<<256, 256, 0, stream>>>(Xb, COSTb);
    k_sinkhorn<<<256, 128, 0, stream>>>(COSTb, QPLANb, QUALb, epoch);
    k_select<<<256, 128, 0, stream>>>(QUALb, QPLANb, rndK, epoch, MASKb);

    // decoder input overwrites Xb
    k_build_x<<<10000, 256, 0, stream>>>(imgs, mtok, MASKb, POSEb, Xb);

    layer(Xb, Xb, 0);
    layer(Xb, Xb, 1);

    // predictor: leaky_relu(x@pW1+pb1)@pW2 (pb2 added in loss)
    k_ffn_mfma<<<200, 256, 0, stream>>>(Xb, PW1T, pb1, PW2T, Yb, 1024, 1);

    k_loss<<<6400, 256, 0, stream>>>(Yb, pb2, imgs, MASKb, LOSSP);
    k_final<<<1, 256, 0, stream>>>(LOSSP, (float*)d_out);
}

// Round 4
// 1108.656 us; speedup vs baseline: 5.0013x; 1.4406x over previous
//
#include <hip/hip_runtime.h>
#include <cmath>
#include <cfloat>

#define B_   256
#define N_   100
#define D_   100
#define BN_  25600

typedef _Float16 f16;
typedef _Float16 f16x8 __attribute__((ext_vector_type(8)));
typedef float    f32x4 __attribute__((ext_vector_type(4)));

// node -> subnet id (partition), from _SUBNET_MAP (1-indexed in python)
__device__ const int d_node2k[100] = {
 0,0,0,0,0,0,0,0,0,
 1,1,1,1,1,1,
 2,2,2,2,2,2,2,2,
 3,3,3,3,3,3,3,
 4,4,4,
 5,5,5,5,
 6,6,6,6,6,6,6,6,6,6,6,6,6,
 0,0,0,0,0,0,0,0,
 1,1,1,1,1,1,1,1,
 2,2,2,2,2,2,2,
 3,3,3,3,3,
 4,4,
 5,5,5,5,5,5,5,5,5,
 6,6,6,6,6,6,6,6,6,6,6};

__device__ __forceinline__ double get_rho(int epoch){
    double t = 1.0 - (double)epoch / 600.0;
    return 0.8 + (1.0 - 0.8) * exp(-5.0 * t * t);
}

// ------------------------- misc small kernels -------------------------
__global__ void k_pos_embed(float* pose){
    int idx = blockIdx.x * blockDim.x + threadIdx.x;
    if (idx >= N_ * D_) return;
    int n = idx / D_;
    int i = idx - n * D_;
    double expo = (double)(2 * (i / 2)) / (double)D_;
    double ang  = (double)n / pow(10000.0, expo);
    pose[idx] = (float)((i & 1) ? cos(ang) : sin(ang));
}

// ------------------------- weight prep -------------------------
// A-side: WT[n][k] (k padded to 128): k<100 = W[k][n], k==100 = bias[n], else 0.
__global__ __launch_bounds__(256) void k_prep_a(const float* __restrict__ W,
        const float* __restrict__ bias, f16* __restrict__ WT, int N, int NP){
    int idx = blockIdx.x * 256 + threadIdx.x;
    if (idx >= NP * 128) return;
    int n = idx >> 7, k = idx & 127;
    float v = 0.f;
    if (n < N){
        if (k < 100) v = W[(size_t)k * N + n];
        else if (k == 100) v = bias[n];
    }
    WT[idx] = (f16)v;
}

// B-side: WT[d][f] (d padded to 112): d<100 = W[f*100+d], else 0.
__global__ __launch_bounds__(256) void k_prep_b(const float* __restrict__ W,
        f16* __restrict__ WT, int F, int lg2F){
    int idx = blockIdx.x * 256 + threadIdx.x;
    if (idx >= 112 * F) return;
    int f = idx & (F - 1);
    int d = idx >> lg2F;
    WT[(size_t)d * F + f] = (d < 100) ? (f16)W[(size_t)f * 100 + d] : (f16)0.f;
}

// ------------------------- MFMA GEMM: out = x_aug @ WT^T -------------------------
// x (25600,100) f32; WT [NP][128] f16 prepped (k=100 holds bias).
// 128 thr = 2 waves x (RT*16) rows. grid.y covers N in chunks of 112.
template<int RT, bool F16OUT>
__global__ __launch_bounds__(128, 2) void k_gemm16(
        const float* __restrict__ x, const f16* __restrict__ WT,
        float* __restrict__ outf, f16* __restrict__ outh, int N){
    __shared__ f16 wls[4 * 112 * 32];   // [ks][n][32k] swizzled, 28KB
    int tid = threadIdx.x;
    int wv = tid >> 6, lane = tid & 63;
    int l15 = lane & 15, lg = lane >> 4;
    int row0 = blockIdx.x * (RT * 32) + wv * (RT * 16);
    int c0 = blockIdx.y * 112;

    // stage WT chunk: 112 rows x 128 k = 1792 uint4
    for (int c = tid; c < 1792; c += 128){
        int n = c >> 4, k8 = c & 15;
        uint4 v = *(const uint4*)(WT + (size_t)(c0 + n) * 128 + k8 * 8);
        *(uint4*)((char*)wls + (k8 >> 2) * 7168 + n * 64 + (((k8 & 3) * 16) ^ ((n & 3) << 4))) = v;
    }

    // x fragments in registers (k-augmented: elem k=100 -> 1.0)
    f16x8 xf[RT][4];
    #pragma unroll
    for (int rt = 0; rt < RT; ++rt){
        const float* xr = x + (size_t)(row0 + rt * 16 + l15) * 100;
        #pragma unroll
        for (int ks = 0; ks < 3; ++ks){
            int k0 = ks * 32 + lg * 8;
            float4 a = *(const float4*)(xr + k0);
            float4 b = *(const float4*)(xr + k0 + 4);
            f16 t[8] = {(f16)a.x,(f16)a.y,(f16)a.z,(f16)a.w,(f16)b.x,(f16)b.y,(f16)b.z,(f16)b.w};
            xf[rt][ks] = *(const f16x8*)t;
        }
        if (lg == 0){
            float4 a = *(const float4*)(xr + 96);
            f16 t[8] = {(f16)a.x,(f16)a.y,(f16)a.z,(f16)a.w,(f16)1.f,(f16)0.f,(f16)0.f,(f16)0.f};
            xf[rt][3] = *(const f16x8*)t;
        } else {
            f16 t[8] = {(f16)0.f,(f16)0.f,(f16)0.f,(f16)0.f,(f16)0.f,(f16)0.f,(f16)0.f,(f16)0.f};
            xf[rt][3] = *(const f16x8*)t;
        }
    }
    __syncthreads();

    f32x4 acc[RT][7];
    #pragma unroll
    for (int rt = 0; rt < RT; ++rt)
        #pragma unroll
        for (int ct = 0; ct < 7; ++ct) acc[rt][ct] = (f32x4)0.f;

    #pragma unroll
    for (int ks = 0; ks < 4; ++ks){
        #pragma unroll
        for (int ct = 0; ct < 7; ++ct){
            int n = ct * 16 + l15;
            f16x8 a = *(const f16x8*)((char*)wls + ks * 7168 + n * 64 + ((lg * 16) ^ ((n & 3) << 4)));
            #pragma unroll
            for (int rt = 0; rt < RT; ++rt)
                acc[rt][ct] = __builtin_amdgcn_mfma_f32_16x16x32_f16(a, xf[rt][ks], acc[rt][ct], 0, 0, 0);
        }
    }

    // epilogue: lane holds 4 consecutive out-cols (col = c0 + ct*16 + lg*4 + reg)
    #pragma unroll
    for (int rt = 0; rt < RT; ++rt){
        int r = row0 + rt * 16 + l15;
        #pragma unroll
        for (int ct = 0; ct < 7; ++ct){
            int col = c0 + ct * 16 + lg * 4;
            if (col + 4 <= N){
                if (F16OUT){
                    f16 t[4] = {(f16)acc[rt][ct][0], (f16)acc[rt][ct][1],
                                (f16)acc[rt][ct][2], (f16)acc[rt][ct][3]};
                    *(uint2*)(outh + (size_t)r * N + col) = *(const uint2*)t;
                } else {
                    *(f32x4*)(outf + (size_t)r * N + col) = acc[rt][ct];
                }
            }
        }
    }
}

// ------------------------- fused FFN (split-F, partial outputs) -------------------------
// x (25600,100) f32; WaT [F][128] f16 (k-aug with bias); WbT [112][F] f16.
// grid (200, 2): 128 rows/block (2 waves x 64), f-half per blockIdx.y.
// P = Pbase + fh*2560000 gets the partial out (f32).
template<int ACT>   // 0 relu, 1 leaky 0.01
__global__ __launch_bounds__(128, 2) void k_ffn2(
        const float* __restrict__ x, const f16* __restrict__ WaT,
        const f16* __restrict__ WbT, float* __restrict__ Pbase, int F){
    __shared__ f16 waTs[4 * 32 * 32];   // [ks][f32][k32] 8KB
    __shared__ f16 wbTs[112 * 32];      // [d][f32] 7KB
    __shared__ f16 hs[2 * 64 * 32];     // [wave][xrow][f32] 8KB
    int tid = threadIdx.x;
    int wv = tid >> 6, lane = tid & 63;
    int l15 = lane & 15, lg = lane >> 4;
    int row0 = blockIdx.x * 128 + wv * 64;
    int fh = blockIdx.y;
    int Fh = F >> 1;
    float* P = Pbase + (size_t)fh * 2560000;

    // x fragments in registers (k-augmented)
    f16x8 xf[4][4];
    #pragma unroll
    for (int rt = 0; rt < 4; ++rt){
        const float* xr = x + (size_t)(row0 + rt * 16 + l15) * 100;
        #pragma unroll
        for (int ks = 0; ks < 3; ++ks){
            int k0 = ks * 32 + lg * 8;
            float4 a = *(const float4*)(xr + k0);
            float4 b = *(const float4*)(xr + k0 + 4);
            f16 t[8] = {(f16)a.x,(f16)a.y,(f16)a.z,(f16)a.w,(f16)b.x,(f16)b.y,(f16)b.z,(f16)b.w};
            xf[rt][ks] = *(const f16x8*)t;
        }
        if (lg == 0){
            float4 a = *(const float4*)(xr + 96);
            f16 t[8] = {(f16)a.x,(f16)a.y,(f16)a.z,(f16)a.w,(f16)1.f,(f16)0.f,(f16)0.f,(f16)0.f};
            xf[rt][3] = *(const f16x8*)t;
        } else {
            f16 t[8] = {(f16)0.f,(f16)0.f,(f16)0.f,(f16)0.f,(f16)0.f,(f16)0.f,(f16)0.f,(f16)0.f};
            xf[rt][3] = *(const f16x8*)t;
        }
    }

    f32x4 acc[4][7];
    #pragma unroll
    for (int rt = 0; rt < 4; ++rt)
        #pragma unroll
        for (int ct = 0; ct < 7; ++ct) acc[rt][ct] = (f32x4)0.f;

    int nch = Fh >> 5;
    for (int ch = 0; ch < nch; ++ch){
        int f0 = fh * Fh + ch * 32;
        __syncthreads();   // previous chunk fully consumed
        // stage WaT chunk: 32 f-rows x 128 k = 512 uint4
        for (int c = tid; c < 512; c += 128){
            int f = c >> 4, k8 = c & 15;
            uint4 v = *(const uint4*)(WaT + (size_t)(f0 + f) * 128 + k8 * 8);
            *(uint4*)((char*)waTs + (k8 >> 2) * 2048 + f * 64 + (((k8 & 3) * 16) ^ ((f & 3) << 4))) = v;
        }
        // stage WbT chunk: 112 d-rows x 32 f = 448 uint4
        for (int c = tid; c < 448; c += 128){
            int d = c >> 2, s = c & 3;
            uint4 v = *(const uint4*)(WbT + (size_t)d * F + f0 + s * 8);
            *(uint4*)((char*)wbTs + d * 64 + ((s * 16) ^ ((d & 3) << 4))) = v;
        }
        __syncthreads();

        // phase 1: H^T(32f x 64 rows) = WaT_chunk . x  (per 16-f subtile)
        #pragma unroll
        for (int ctp = 0; ctp < 2; ++ctp){
            f32x4 h[4];
            #pragma unroll
            for (int rt = 0; rt < 4; ++rt) h[rt] = (f32x4)0.f;
            #pragma unroll
            for (int ks = 0; ks < 4; ++ks){
                int fl = ctp * 16 + l15;
                f16x8 a = *(const f16x8*)((char*)waTs + ks * 2048 + fl * 64 + ((lg * 16) ^ ((fl & 3) << 4)));
                #pragma unroll
                for (int rt = 0; rt < 4; ++rt)
                    h[rt] = __builtin_amdgcn_mfma_f32_16x16x32_f16(a, xf[rt][ks], h[rt], 0, 0, 0);
            }
            // act + f16 pack; lane holds f = ctp*16 + lg*4 + reg for xrow rt*16+l15
            #pragma unroll
            for (int rt = 0; rt < 4; ++rt){
                f16 t[4];
                #pragma unroll
                for (int reg = 0; reg < 4; ++reg){
                    float v = h[rt][reg];
                    v = (v > 0.f) ? v : (ACT ? 0.01f * v : 0.f);
                    t[reg] = (f16)v;
                }
                int xr = rt * 16 + l15;
                *(uint2*)((char*)hs + wv * 4096 + xr * 64 + ((ctp * 32 + lg * 8) ^ ((xr & 3) << 4))) = *(const uint2*)t;
            }
        }
        // phase 2: acc += WbT_chunk . H^T   (H as B-operand, direct b128 reads)
        f16x8 bf[4];
        #pragma unroll
        for (int rt = 0; rt < 4; ++rt){
            int xr = rt * 16 + l15;
            bf[rt] = *(const f16x8*)((char*)hs + wv * 4096 + xr * 64 + ((lg * 16) ^ ((xr & 3) << 4)));
        }
        #pragma unroll
        for (int ct = 0; ct < 7; ++ct){
            int d = ct * 16 + l15;
            f16x8 a2 = *(const f16x8*)((char*)wbTs + d * 64 + ((lg * 16) ^ ((d & 3) << 4)));
            #pragma unroll
            for (int rt = 0; rt < 4; ++rt)
                acc[rt][ct] = __builtin_amdgcn_mfma_f32_16x16x32_f16(a2, bf[rt], acc[rt][ct], 0, 0, 0);
        }
    }

    // epilogue: partial out (f32), 4 consecutive cols per lane
    #pragma unroll
    for (int rt = 0; rt < 4; ++rt){
        int r = row0 + rt * 16 + l15;
        #pragma unroll
        for (int ct = 0; ct < 7; ++ct){
            int col = ct * 16 + lg * 4;
            if (col < 100)
                *(f32x4*)(P + (size_t)r * 100 + col) = acc[rt][ct];
        }
    }
}

// ------------------------- attention (per b,head), f16 qkv -------------------------
__global__ __launch_bounds__(128) void k_attn(const f16* __restrict__ qkv,
                                              float* __restrict__ o){
    int b = blockIdx.x >> 2;
    int h = blockIdx.x & 3;
    __shared__ float ks[100][26];
    __shared__ float vs[100][26];
    for (int i = threadIdx.x; i < 2500; i += 128){
        int n = i / 25, d = i - n * 25;
        const f16* base = qkv + (size_t)(b * 100 + n) * 300 + h * 25 + d;
        ks[n][d] = (float)base[100];
        vs[n][d] = (float)base[200];
    }
    __syncthreads();
    int n = threadIdx.x;
    if (n < 100){
        float q[25];
        const f16* qb = qkv + (size_t)(b * 100 + n) * 300 + h * 25;
        #pragma unroll
        for (int d = 0; d < 25; ++d) q[d] = (float)qb[d];
        float m = -FLT_MAX, l = 0.f, acc[25];
        #pragma unroll
        for (int d = 0; d < 25; ++d) acc[d] = 0.f;
        for (int c = 0; c < 100; ++c){
            float s = 0.f;
            #pragma unroll
            for (int d = 0; d < 25; ++d) s += q[d] * ks[c][d];
            s *= 0.2f;
            if (s <= m){
                float p = expf(s - m);
                l += p;
                #pragma unroll
                for (int d = 0; d < 25; ++d) acc[d] += p * vs[c][d];
            } else {
                float sc = expf(m - s);
                l = l * sc + 1.f;
                #pragma unroll
                for (int d = 0; d < 25; ++d) acc[d] = acc[d] * sc + vs[c][d];
                m = s;
            }
        }
        float inv = 1.f / l;
        float* ob = o + (size_t)(b * 100 + n) * 100 + h * 25;
        #pragma unroll
        for (int d = 0; d < 25; ++d) ob[d] = acc[d] * inv;
    }
}

// ------------------------- fused add + LayerNorm (2 or 3 inputs) -------------------------
__global__ __launch_bounds__(256) void k_add_ln(
        const float* __restrict__ xa, const float* __restrict__ xb,
        const float* __restrict__ xc, const float* __restrict__ bias,
        const float* __restrict__ g, const float* __restrict__ bt,
        float* __restrict__ out){
    int row  = blockIdx.x * 4 + (threadIdx.x >> 6);
    int lane = threadIdx.x & 63;
    const float* pa = xa + (size_t)row * 100;
    const float* pb = xb + (size_t)row * 100;
    int e1 = lane + 64;
    float v0 = pa[lane] + pb[lane];
    float v1 = (e1 < 100) ? (pa[e1] + pb[e1]) : 0.f;
    if (xc){
        const float* pc = xc + (size_t)row * 100;
        v0 += pc[lane];
        if (e1 < 100) v1 += pc[e1];
    }
    if (bias){
        v0 += bias[lane];
        if (e1 < 100) v1 += bias[e1];
    }
    float s = v0 + v1;
    #pragma unroll
    for (int m = 32; m >= 1; m >>= 1) s += __shfl_xor(s, m, 64);
    float mean = s / 100.f;
    float d0 = v0 - mean;
    float d1 = (e1 < 100) ? (v1 - mean) : 0.f;
    float s2 = d0 * d0 + d1 * d1;
    #pragma unroll
    for (int m = 32; m >= 1; m >>= 1) s2 += __shfl_xor(s2, m, 64);
    float rstd = 1.f / sqrtf(s2 / 100.f + 1e-5f);
    float* po = out + (size_t)row * 100;
    po[lane] = d0 * rstd * g[lane] + bt[lane];
    if (e1 < 100) po[e1] = d1 * rstd * g[e1] + bt[e1];
}

// ------------------------- subnet means + cosine cost -------------------------
__global__ __launch_bounds__(256) void k_subnet_cost(const float* __restrict__ feat,
                                                     float* __restrict__ cost){
    int b = blockIdx.x;
    __shared__ float fs[100][101];
    __shared__ float sf[7][101];
    __shared__ float nf[100];
    __shared__ float ns[7];
    int tid = threadIdx.x;
    for (int idx = tid; idx < 10000; idx += 256){
        int n = idx / 100, d = idx - n * 100;
        fs[n][d] = feat[(size_t)(b * 100 + n) * 100 + d];
    }
    __syncthreads();
    const float cnt[7] = {17.f, 14.f, 15.f, 12.f, 5.f, 13.f, 24.f};
    for (int idx = tid; idx < 700; idx += 256){
        int k = idx / 100, d = idx - k * 100;
        float s = 0.f;
        for (int n = 0; n < 100; ++n) if (d_node2k[n] == k) s += fs[n][d];
        sf[k][d] = s / (cnt[k] + 1e-6f);
    }
    __syncthreads();
    if (tid < 100){
        float s = 0.f;
        for (int d = 0; d < 100; ++d) s += fs[tid][d] * fs[tid][d];
        float nv = sqrtf(s);
        nf[tid] = nv > 1e-12f ? nv : 1e-12f;
    }
    if (tid >= 128 && tid < 135){
        int k = tid - 128;
        float s = 0.f;
        for (int d = 0; d < 100; ++d) s += sf[k][d] * sf[k][d];
        float nv = sqrtf(s);
        ns[k] = nv > 1e-12f ? nv : 1e-12f;
    }
    __syncthreads();
    for (int idx = tid; idx < 700; idx += 256){
        int n = idx / 7, k = idx - n * 7;
        float s = 0.f;
        for (int d = 0; d < 100; ++d) s += fs[n][d] * sf[k][d];
        cost[(size_t)b * 700 + n * 7 + k] = s / (nf[n] * ns[k]);
    }
}

// ------------------------- sinkhorn (f64, per image, cold start) -------------------------
__global__ __launch_bounds__(128) void k_sinkhorn(const float* __restrict__ cost,
        float* __restrict__ qplan, float* __restrict__ qual,
        const int* __restrict__ ep){
    int b   = blockIdx.x;
    int tid = threadIdx.x;
    __shared__ double Qm[100][8];
    __shared__ double av[100];
    __shared__ double bv[8];
    __shared__ double b2v[8];
    __shared__ int s_stop;
    double rho = get_rho(ep[0]);
    const double prior[7] = {17.0/100.0, 14.0/100.0, 15.0/100.0, 12.0/100.0,
                             5.0/100.0, 13.0/100.0, 24.0/100.0};
    if (tid < 100){
        double c[7]; double mx = -1e300;
        for (int k = 0; k < 7; ++k){
            c[k] = (double)cost[(size_t)b * 700 + tid * 7 + k];
            if (c[k] > mx) mx = c[k];
        }
        double se = 0.0;
        for (int k = 0; k < 7; ++k) se += exp(c[k] - mx);
        double lse = mx + log(se);
        for (int k = 0; k < 7; ++k) Qm[tid][k] = exp(-((lse - c[k]) / 0.1));
        Qm[tid][7] = 1.0;
    }
    if (tid < 8) bv[tid] = 1.0 / 8.0;
    if (tid == 0) s_stop = 0;
    __syncthreads();
    const double fi = 1.0 / 1.1;
    int j = tid >> 4, l16 = tid & 15;
    double Pbj = (j < 7) ? rho * prior[j] : (1.0 - rho);
    for (int it = 0; it < 50; ++it){
        if (tid < 100){
            double s = 0.0;
            #pragma unroll
            for (int k = 0; k < 8; ++k) s += Qm[tid][k] * bv[k];
            av[tid] = 0.01 / s;
        }
        __syncthreads();
        double p = 0.0;
        for (int n = l16; n < 100; n += 16) p += Qm[n][j] * av[n];
        p += __shfl_xor(p, 8, 16);
        p += __shfl_xor(p, 4, 16);
        p += __shfl_xor(p, 2, 16);
        p += __shfl_xor(p, 1, 16);
        if (l16 == 0){
            double nb = Pbj / p;
            if (j < 7) nb = pow(nb, fi);
            b2v[j] = nb;
        }
        __syncthreads();
        if (tid == 0){
            double e2 = 0.0;
            #pragma unroll
            for (int k = 0; k < 8; ++k){
                double d = b2v[k] - bv[k];
                e2 += d * d;
                bv[k] = b2v[k];
            }
            s_stop = (e2 <= 1e-12) ? 1 : 0;
        }
        __syncthreads();
        if (s_stop) break;
    }
    if (tid < 100){
        float q = 0.f;
        for (int k = 0; k < 7; ++k){
            double pl = 100.0 * av[tid] * Qm[tid][k] * bv[k];
            float pf = (float)pl;
            qplan[(size_t)b * 700 + tid * 7 + k] = pf;
            q += pf;
        }
        qual[(size_t)b * 100 + tid] = q;
    }
}

// ------------------------- selection -------------------------
__global__ __launch_bounds__(128) void k_select(const float* __restrict__ qual,
        const float* __restrict__ qplan, const float* __restrict__ randK,
        const int* __restrict__ ep, float* __restrict__ maskb){
    int b   = blockIdx.x;
    int tid = threadIdx.x;
    __shared__ float qs[100];
    __shared__ float sorted_s[100];
    __shared__ float noise_s[100];
    __shared__ float thr_f;
    if (tid < 100) qs[tid] = qual[(size_t)b * 100 + tid];
    __syncthreads();
    if (tid < 100){
        float q = qs[tid];
        int cl = 0, ce = 0;
        for (int m = 0; m < 100; ++m){ cl += (qs[m] < q); ce += (qs[m] == q); }
        for (int r2 = cl; r2 < cl + ce; ++r2) sorted_s[r2] = q;
    }
    __syncthreads();
    if (tid == 0){
        double rho = get_rho(ep[0]);
        double pos = (1.0 - rho) * 99.0;
        int lo = (int)floor(pos);
        if (lo > 98) lo = 98; if (lo < 0) lo = 0;
        double fr = pos - (double)lo;
        double thr = (double)sorted_s[lo] + ((double)sorted_s[lo + 1] - (double)sorted_s[lo]) * fr;
        thr_f = (float)thr;
    }
    __syncthreads();
    if (tid < 100){
        float nz = 0.f;
        if (!(qs[tid] < thr_f)){
            for (int k = 0; k < 7; ++k)
                nz += qplan[(size_t)b * 700 + tid * 7 + k] * randK[b * 7 + k];
        }
        noise_s[tid] = nz;
    }
    __syncthreads();
    if (tid < 100){
        float nz = noise_s[tid];
        int rk = 0;
        for (int m = 0; m < 100; ++m){
            rk += (noise_s[m] < nz);
            rk += ((noise_s[m] == nz) && (m < tid));
        }
        maskb[(size_t)b * 100 + tid] = (rk >= 90) ? 1.f : 0.f;
    }
}

// ------------------------- build decoder input -------------------------
__global__ void k_build_x(const float* __restrict__ imgs, const float* __restrict__ mtok,
        const float* __restrict__ maskb, const float* __restrict__ pose,
        float* __restrict__ x){
    int idx = blockIdx.x * 256 + threadIdx.x;
    if (idx >= B_ * N_ * D_) return;
    int d  = idx % 100;
    int bn = idx / 100;
    int n  = bn % 100;
    float v = (maskb[bn] == 0.f) ? imgs[idx] : mtok[d];
    x[idx] = v + pose[n * 100 + d];
}

// ------------------------- loss: two-stage reduction -------------------------
__global__ __launch_bounds__(256) void k_loss(const float* __restrict__ p1,
        const float* __restrict__ p2, const float* __restrict__ pb2,
        const float* __restrict__ imgs, const float* __restrict__ maskb,
        double* __restrict__ partial){
    int wv   = threadIdx.x >> 6;
    int row  = blockIdx.x * 4 + wv;
    int lane = threadIdx.x & 63;
    const float* pp = p1 + (size_t)row * 100;
    const float* pq = p2 + (size_t)row * 100;
    const float* pi = imgs + (size_t)row * 100;
    float d0 = pp[lane] + pq[lane] + pb2[lane] - pi[lane];
    float s = d0 * d0;
    int e1 = lane + 64;
    if (e1 < 100){
        float d1 = pp[e1] + pq[e1] + pb2[e1] - pi[e1];
        s += d1 * d1;
    }
    #pragma unroll
    for (int m = 32; m >= 1; m >>= 1) s += __shfl_xor(s, m, 64);
    __shared__ float ls[4], lc[4];
    if (lane == 0){
        float mk = maskb[row];
        ls[wv] = (s / 100.f) * mk;
        lc[wv] = mk;
    }
    __syncthreads();
    if (threadIdx.x == 0){
        partial[2 * blockIdx.x]     = (double)(ls[0] + ls[1] + ls[2] + ls[3]);
        partial[2 * blockIdx.x + 1] = (double)(lc[0] + lc[1] + lc[2] + lc[3]);
    }
}

__global__ __launch_bounds__(256) void k_final(const double* __restrict__ partial,
                                               float* __restrict__ out){
    int tid = threadIdx.x;
    double s = 0.0, c = 0.0;
    for (int i = tid; i < 6400; i += 256){
        s += partial[2 * i];
        c += partial[2 * i + 1];
    }
    #pragma unroll
    for (int m = 32; m >= 1; m >>= 1){
        s += __shfl_xor(s, m, 64);
        c += __shfl_xor(c, m, 64);
    }
    __shared__ double ss[4], cs[4];
    if ((tid & 63) == 0){ ss[tid >> 6] = s; cs[tid >> 6] = c; }
    __syncthreads();
    if (tid == 0){
        double S = ss[0] + ss[1] + ss[2] + ss[3];
        double C = cs[0] + cs[1] + cs[2] + cs[3];
        out[0] = (float)(S / C);
    }
}

// ------------------------- host -------------------------
extern "C" void kernel_launch(void* const* d_in, const int* in_sizes, int n_in,
                              void* d_out, int out_size, void* d_ws, size_t ws_size,
                              hipStream_t stream){
    const float* imgs = (const float*)d_in[0];
    const float* Wqkv = (const float*)d_in[1];
    const float* bqkv = (const float*)d_in[2];
    const float* Wo   = (const float*)d_in[3];
    const float* bo   = (const float*)d_in[4];
    const float* ln1g = (const float*)d_in[5];
    const float* ln1b = (const float*)d_in[6];
    const float* W1   = (const float*)d_in[7];
    const float* b1   = (const float*)d_in[8];
    const float* W2   = (const float*)d_in[9];
    const float* b2   = (const float*)d_in[10];
    const float* ln2g = (const float*)d_in[11];
    const float* ln2b = (const float*)d_in[12];
    const float* mtok = (const float*)d_in[13];
    const float* pW1  = (const float*)d_in[14];
    const float* pb1  = (const float*)d_in[15];
    const float* pW2  = (const float*)d_in[16];
    const float* pb2  = (const float*)d_in[17];
    const float* rndK = (const float*)d_in[18];
    const int*   epoch = (const int*)d_in[19];

    float* ws   = (float*)d_ws;
    float* Xb   = ws;                         // 2,560,000 f32
    float* P1   = Xb + 2560000;               // 2,560,000 f32 (attn out / ffn partial 1)
    float* P2   = P1 + 2560000;               // 2,560,000 f32 (Wo out / ffn partial 2)
    f16*   QKVh = (f16*)(P2 + 2560000);       // 7,680,000 f16 (spans 3,840,000 f32)
    // overlay (dead while QKVh idle between encoder and decoder):
    float* COSTb  = P2 + 2560000;             // 179,200
    float* QPLANb = COSTb + 179200;           // 179,200
    float* QUALb  = QPLANb + 179200;          // 25,600
    float* WARENA = P2 + 2560000 + 3840000;   // f16 arena start
    f16* wh = (f16*)WARENA;
    f16* WqkvT0 = wh;               wh += 43008;    // 336*128
    f16* WqkvT1 = wh;               wh += 43008;
    f16* WoT0   = wh;               wh += 14336;    // 112*128
    f16* WoT1   = wh;               wh += 14336;
    f16* W1T0   = wh;               wh += 262144;   // 2048*128
    f16* W1T1   = wh;               wh += 262144;
    f16* W2T0   = wh;               wh += 229376;   // 112*2048
    f16* W2T1   = wh;               wh += 229376;
    f16* PW1T   = wh;               wh += 131072;   // 1024*128
    f16* PW2T   = wh;               wh += 114688;   // 112*1024
    float* tail = WARENA + 671744;
    float* MASKb = tail;            tail += 25600;
    float* POSEb = tail;            tail += 10000;
    double* LOSSP = (double*)tail;  // 6400*2 doubles

    // one-time weight prep
    k_prep_a<<<168,  256, 0, stream>>>(Wqkv,          bqkv,       WqkvT0, 300, 336);
    k_prep_a<<<168,  256, 0, stream>>>(Wqkv + 30000,  bqkv + 300, WqkvT1, 300, 336);
    k_prep_a<<<56,   256, 0, stream>>>(Wo,            bo,         WoT0,   100, 112);
    k_prep_a<<<56,   256, 0, stream>>>(Wo + 10000,    bo + 100,   WoT1,   100, 112);
    k_prep_a<<<1024, 256, 0, stream>>>(W1,            b1,         W1T0,  2048, 2048);
    k_prep_a<<<1024, 256, 0, stream>>>(W1 + 204800,   b1 + 2048,  W1T1,  2048, 2048);
    k_prep_b<<<896,  256, 0, stream>>>(W2,          W2T0, 2048, 11);
    k_prep_b<<<896,  256, 0, stream>>>(W2 + 204800, W2T1, 2048, 11);
    k_prep_a<<<512,  256, 0, stream>>>(pW1, pb1, PW1T, 1024, 1024);
    k_prep_b<<<448,  256, 0, stream>>>(pW2, PW2T, 1024, 10);
    k_pos_embed<<<79, 128, 0, stream>>>(POSEb);

    auto layer = [&](const float* xi, float* xo, int l){
        k_gemm16<4, true><<<dim3(200, 3), 128, 0, stream>>>(
            xi, l ? WqkvT1 : WqkvT0, nullptr, QKVh, 300);
        k_attn<<<1024, 128, 0, stream>>>(QKVh, P1);
        k_gemm16<2, false><<<dim3(400, 1), 128, 0, stream>>>(
            P1, l ? WoT1 : WoT0, P2, nullptr, 100);
        k_add_ln<<<6400, 256, 0, stream>>>(xi, P2, nullptr, nullptr,
            ln1g + l * 100, ln1b + l * 100, xo);
        k_ffn2<0><<<dim3(200, 2), 128, 0, stream>>>(
            xo, l ? W1T1 : W1T0, l ? W2T1 : W2T0, P1, 2048);
        k_add_ln<<<6400, 256, 0, stream>>>(xo, P1, P2, b2 + l * 100,
            ln2g + l * 100, ln2b + l * 100, xo);
    };

    // encoder on stop_gradient(imgs) -> feat in Xb
    layer(imgs, Xb, 0);
    layer(Xb, Xb, 1);

    k_subnet_cost<<<256, 256, 0, stream>>>(Xb, COSTb);
    k_sinkhorn<<<256, 128, 0, stream>>>(COSTb, QPLANb, QUALb, epoch);
    k_select<<<256, 128, 0, stream>>>(QUALb, QPLANb, rndK, epoch, MASKb);

    // decoder input overwrites Xb
    k_build_x<<<10000, 256, 0, stream>>>(imgs, mtok, MASKb, POSEb, Xb);

    layer(Xb, Xb, 0);
    layer(Xb, Xb, 1);

    // predictor: leaky_relu(x@pW1+pb1)@pW2 -> partials P1,P2 (pb2 added in loss)
    k_ffn2<1><<<dim3(200, 2), 128, 0, stream>>>(Xb, PW1T, PW2T, P1, 1024);

    k_loss<<<6400, 256, 0, stream>>>(P1, P2, pb2, imgs, MASKb, LOSSP);
    k_final<<<1, 256, 0, stream>>>(LOSSP, (float*)d_out);
}